// Round 6
// baseline (90.002 us; speedup 1.0000x reference)
//
#include <hip/hip_runtime.h>
#include <hip/hip_cooperative_groups.h>
#include <math.h>

namespace cg = cooperative_groups;

#define B 32
#define T 262144
#define NFR 250
#define NTHR 256

// ---- fused (cooperative) config ----
#define FNCH 16                  // chunks per row
#define FCHUNK 16384             // elements per block
#define FNBLK (B * FNCH)         // 512 blocks: 2/CU needed, capacity 4/CU
#define NRUN 4                   // runs per thread
#define RUNE 16                  // elements per run; run (h,t) at h*4096 + t*16

// ---- fallback (round-4 validated) config ----
#define NCH 64
#define CHUNK 4096
#define EPT 16

// [256][16] f32 tile swizzle: XOR on e bits [3:2] keeps float4 alignment and
// spreads both per-owner b128 and linear coalesced b128 across banks.
__device__ __forceinline__ int swz16(int t, int e) {
  return t * 16 + (e ^ ((t & 3) << 2));
}

// Per-op envelope line params at local frame i0s: env*mi = c0 + s0*pr + dd*max(pr-1,0)
__device__ __forceinline__ void env_params(const float* __restrict__ adsr,
                                           int row, int k, int i0s, float em,
                                           float& c0, float& s0, float& dd) {
  const float* ap = adsr + row * 11 + k;
  float fl = ap[0], pk = ap[1];
  float a = fmaxf(ap[2], 1e-5f);
  float de = fmaxf(ap[3], 1e-5f);
  float ss = ap[4];
  float r = fmaxf(ap[5], 1e-5f);
  float ra = 1.0f / a, rd = 1.0f / de, rr = 1.0f / r;
  float e3[3];
#pragma unroll
  for (int j = 0; j < 3; ++j) {
    int fi = i0s + j;
    fi = (fi < NFR - 1) ? fi : NFR - 1;
    float tt = (float)fi * (1.0f / 249.0f);
    float att = fminf(fmaxf(tt * ra, 0.0f), 1.0f);
    float dec = fminf(fmaxf((tt - a) * rd, 0.0f), 1.0f);
    float rel = fminf(fmaxf((tt - (1.0f - r)) * rr, 0.0f), 1.0f);
    float env = att * (1.0f - (1.0f - ss) * dec) * (1.0f - rel);
    e3[j] = fl + (pk - fl) * env;
  }
  c0 = e3[0] * em;
  s0 = (e3[1] - e3[0]) * em;
  dd = (e3[2] - e3[1]) * em - s0;
}

// ==================== fused cooperative kernel ====================
__global__ __launch_bounds__(NTHR, 4) void k_fused(
    const float* __restrict__ f0, const float* __restrict__ mod_index,
    const float* __restrict__ freq_ratio, const float* __restrict__ adsr,
    double* __restrict__ partials, float* __restrict__ out) {
  __shared__ __align__(16) float tile[NTHR * RUNE];  // 16 KB
  __shared__ double wsh[NRUN][NTHR / 64];

  int bx = blockIdx.x;
  int row = bx >> 4, ch = bx & 15;
  int t = threadIdx.x, lane = t & 63, wid = t >> 6;
  size_t rowOff = (size_t)row * T;
  const float* cptr = f0 + rowOff + ch * FCHUNK;

  // ---- phase A: per-run sums + wave scans (f64) ----
  double xx[NRUN], ts[NRUN];
#pragma unroll
  for (int h = 0; h < NRUN; ++h) {
    const float4* p = (const float4*)(cptr + h * 4096 + t * RUNE);
    float fs = 0.0f;
#pragma unroll
    for (int q = 0; q < 4; ++q) {
      float4 x = p[q];
      fs += (x.x + x.y) + (x.z + x.w);
    }
    ts[h] = (double)fs;
    double v = ts[h];
#pragma unroll
    for (int d = 1; d < 64; d <<= 1) {
      double n = __shfl_up(v, d);
      if (lane >= d) v += n;
    }
    xx[h] = v;
    if (lane == 63) wsh[h][wid] = v;
  }
  __syncthreads();

  double pfxh[NRUN];
  double runacc = 0.0;
#pragma unroll
  for (int h = 0; h < NRUN; ++h) {
    double wb = 0.0, th = 0.0;
#pragma unroll
    for (int w = 0; w < NTHR / 64; ++w) {
      double s = wsh[h][w];
      wb += (w < wid) ? s : 0.0;
      th += s;
    }
    pfxh[h] = runacc + wb + (xx[h] - ts[h]);  // block-local exclusive prefix
    runacc += th;                              // chunk total so far
  }
  if (t == 0)
    __hip_atomic_store(&partials[bx], runacc, __ATOMIC_RELAXED,
                       __HIP_MEMORY_SCOPE_AGENT);

  // row-uniform op constants (overlaps other blocks' phase A)
  float frs[6], em[6];
#pragma unroll
  for (int k = 0; k < 6; ++k) {
    frs[k] = freq_ratio[row * 6 + k] * (1.0f / 16000.0f);
    em[k] = 2.0f / (1.0f + expf(-mod_index[row * 6 + k]));
  }

  // ---- grid-wide sync: all chunk totals published ----
  cg::this_grid().sync();

  // chunk base: wave-parallel reduce of preceding chunk totals
  double pv = 0.0;
  if (lane < ch)
    pv = __hip_atomic_load(&partials[(row << 4) + lane], __ATOMIC_RELAXED,
                           __HIP_MEMORY_SCOPE_AGENT);
#pragma unroll
  for (int d = 32; d > 0; d >>= 1) pv += __shfl_down(pv, d);
  double cb = __shfl(pv, 0);

  const float step = 249.0f / (float)(T - 1);

  // ---- phase B: per-run FM chain, staged store ----
#pragma unroll 1
  for (int h = 0; h < NRUN; ++h) {
    float s = (float)(cb + pfxh[h]);  // exclusive raw-f0 prefix for this run

    int i0 = ch * FCHUNK + h * 4096 + t * RUNE;
    int i0s = (int)floorf((float)i0 * step);
    float pr = (float)i0 * step - (float)i0s;  // local frame coord, seg0 pr<1
    float c0[6], s0[6], dd6[6];
#pragma unroll
    for (int k = 0; k < 6; ++k)
      env_params(adsr, row, k, i0s, em[k], c0[k], s0[k], dd6[k]);

    const float4* p = (const float4*)(cptr + h * 4096 + t * RUNE);
#pragma unroll
    for (int q = 0; q < 4; ++q) {
      float4 v = p[q];  // L2-warm reload
      float res[4];
#pragma unroll
      for (int j = 0; j < 4; ++j) {
        float f0v = (j == 0) ? v.x : (j == 1) ? v.y : (j == 2) ? v.z : v.w;
        s += f0v;                          // inclusive raw prefix
        float m = fmaxf(pr - 1.0f, 0.0f);  // shared hinge

        auto opk = [&](int k, float mod) {
          float ph = fmaf(frs[k], s, mod);  // revolutions
          float sv = __builtin_amdgcn_sinf(__builtin_amdgcn_fractf(ph));
          float e = fmaf(m, dd6[k], fmaf(pr, s0[k], c0[k]));
          return sv * e;
        };

        float o6 = opk(5, 0.0f);
        float o2 = opk(1, 0.0f);
        float o5 = opk(4, o6);
        float o1 = opk(0, o2);
        float o4 = opk(3, o5);
        float o3 = opk(2, o4);
        res[j] = (o3 + o1) * 0.5f;
        pr += step;
      }
      float4 ov;
      ov.x = res[0]; ov.y = res[1]; ov.z = res[2]; ov.w = res[3];
      *(float4*)&tile[swz16(t, 4 * q)] = ov;
    }
    __syncthreads();  // run staged

    float4* ob = (float4*)(out + rowOff + ch * FCHUNK + h * 4096);
#pragma unroll
    for (int i = 0; i < 4; ++i) {
      int li = i * 1024 + t * 4;
      int tt = li >> 4, ee = li & 15;
      ob[i * NTHR + t] = *(const float4*)&tile[swz16(tt, ee)];
    }
    __syncthreads();  // tile free for next run
  }
}

// ==================== fallback: round-4 validated pair ====================
__global__ __launch_bounds__(NTHR) void k_partial(const float* __restrict__ f0,
                                                  double* __restrict__ partials) {
  int row = blockIdx.y, ch = blockIdx.x, t = threadIdx.x;
  const float4* p = (const float4*)(f0 + (size_t)row * T + ch * CHUNK);
  double s = 0.0;
#pragma unroll
  for (int i = 0; i < CHUNK / 4 / NTHR; ++i) {
    float4 v = p[i * NTHR + t];
    s += (double)v.x + (double)v.y + (double)v.z + (double)v.w;
  }
#pragma unroll
  for (int d = 32; d > 0; d >>= 1) s += __shfl_down(s, d);
  __shared__ double wsum[NTHR / 64];
  int lane = t & 63, wid = t >> 6;
  if (lane == 0) wsum[wid] = s;
  __syncthreads();
  if (t == 0) {
    double tot = 0.0;
#pragma unroll
    for (int w = 0; w < NTHR / 64; ++w) tot += wsum[w];
    __hip_atomic_store(&partials[row * NCH + ch], tot, __ATOMIC_RELAXED,
                       __HIP_MEMORY_SCOPE_AGENT);
  }
}

__global__ __launch_bounds__(NTHR, 8) void k_main(const float* __restrict__ f0,
                                                  const float* __restrict__ mod_index,
                                                  const float* __restrict__ freq_ratio,
                                                  const float* __restrict__ adsr,
                                                  const double* __restrict__ partials,
                                                  float* __restrict__ out) {
  __shared__ __align__(16) float tile[NTHR * EPT];
  __shared__ double wsum[NTHR / 64];

  int row = blockIdx.y, ch = blockIdx.x, t = threadIdx.x;
  int lane = t & 63, wid = t >> 6;
  size_t rowOff = (size_t)row * T;

  const float4* fp4 = (const float4*)(f0 + rowOff + ch * CHUNK);
#pragma unroll
  for (int i = 0; i < 4; ++i) {
    float4 v = fp4[i * NTHR + t];
    int tt = i * 64 + (t >> 2);
    int ee = (t & 3) * 4;
    *(float4*)&tile[swz16(tt, ee)] = v;
  }
  __syncthreads();

  float fsum = 0.0f;
#pragma unroll
  for (int q = 0; q < 4; ++q) {
    float4 v = *(const float4*)&tile[swz16(t, 4 * q)];
    fsum += (v.x + v.y) + (v.z + v.w);
  }
  double ts = (double)fsum;

  double x = ts;
#pragma unroll
  for (int d = 1; d < 64; d <<= 1) {
    double n = __shfl_up(x, d);
    if (lane >= d) x += n;
  }
  if (lane == 63) wsum[wid] = x;

  double pv = 0.0;
  if (lane < ch && lane < 64)
    pv = __hip_atomic_load(&partials[row * NCH + lane], __ATOMIC_RELAXED,
                           __HIP_MEMORY_SCOPE_AGENT);
#pragma unroll
  for (int d = 32; d > 0; d >>= 1) pv += __shfl_down(pv, d);
  double cb = __shfl(pv, 0);
  // NCH=64 > wave width: add chunks 32..63 via second wave segment when ch>32
  if (NCH > 32) {
    double pv2 = 0.0;
    int idx = 32 + lane;
    if (idx < ch)
      pv2 = __hip_atomic_load(&partials[row * NCH + idx], __ATOMIC_RELAXED,
                              __HIP_MEMORY_SCOPE_AGENT);
#pragma unroll
    for (int d = 32; d > 0; d >>= 1) pv2 += __shfl_down(pv2, d);
    cb += __shfl(pv2, 0);
  }

  __syncthreads();
  double wbase = 0.0;
#pragma unroll
  for (int w = 0; w < NTHR / 64; ++w) wbase += (w < wid) ? wsum[w] : 0.0;
  float s = (float)(cb + wbase + (x - ts));

  const float step = 249.0f / (float)(T - 1);
  int i0 = ch * CHUNK + t * EPT;
  int i0s = (int)floorf((float)i0 * step);
  float pr = (float)i0 * step - (float)i0s;

  float frs[6], c0[6], s0[6], dd6[6];
#pragma unroll
  for (int k = 0; k < 6; ++k) {
    frs[k] = freq_ratio[row * 6 + k] * (1.0f / 16000.0f);
    float em = 2.0f / (1.0f + expf(-mod_index[row * 6 + k]));
    env_params(adsr, row, k, i0s, em, c0[k], s0[k], dd6[k]);
  }

#pragma unroll
  for (int q = 0; q < 4; ++q) {
    float4 v = *(const float4*)&tile[swz16(t, 4 * q)];
    float res[4];
#pragma unroll
    for (int j = 0; j < 4; ++j) {
      float f0v = (j == 0) ? v.x : (j == 1) ? v.y : (j == 2) ? v.z : v.w;
      s += f0v;
      float m = fmaxf(pr - 1.0f, 0.0f);
      auto opk = [&](int k, float mod) {
        float ph = fmaf(frs[k], s, mod);
        float sv = __builtin_amdgcn_sinf(__builtin_amdgcn_fractf(ph));
        float e = fmaf(m, dd6[k], fmaf(pr, s0[k], c0[k]));
        return sv * e;
      };
      float o6 = opk(5, 0.0f);
      float o2 = opk(1, 0.0f);
      float o5 = opk(4, o6);
      float o1 = opk(0, o2);
      float o4 = opk(3, o5);
      float o3 = opk(2, o4);
      res[j] = (o3 + o1) * 0.5f;
      pr += step;
    }
    float4 ov;
    ov.x = res[0]; ov.y = res[1]; ov.z = res[2]; ov.w = res[3];
    *(float4*)&tile[swz16(t, 4 * q)] = ov;
  }
  __syncthreads();

  float4* ob = (float4*)(out + rowOff + ch * CHUNK);
#pragma unroll
  for (int i = 0; i < 4; ++i) {
    int tt = i * 64 + (t >> 2);
    int ee = (t & 3) * 4;
    ob[i * NTHR + t] = *(const float4*)&tile[swz16(tt, ee)];
  }
}

extern "C" void kernel_launch(void* const* d_in, const int* in_sizes, int n_in,
                              void* d_out, int out_size, void* d_ws, size_t ws_size,
                              hipStream_t stream) {
  const float* mod_index  = (const float*)d_in[0]; // [32,6]
  const float* freq_ratio = (const float*)d_in[1]; // [32,6]
  const float* f0         = (const float*)d_in[2]; // [32,T]
  const float* adsr       = (const float*)d_in[3]; // [32,11]
  float* out = (float*)d_out;
  double* partials = (double*)d_ws;  // fused: 512*8 B; fallback: 2048*8 B

  void* args[] = {(void*)&f0, (void*)&mod_index, (void*)&freq_ratio,
                  (void*)&adsr, (void*)&partials, (void*)&out};
  hipError_t rc = hipLaunchCooperativeKernel((void*)k_fused, dim3(FNBLK),
                                             dim3(NTHR), args, 0, stream);
  if (rc != hipSuccess) {
    (void)hipGetLastError();  // clear sticky error, take validated 2-kernel path
    hipLaunchKernelGGL(k_partial, dim3(NCH, B), dim3(NTHR), 0, stream, f0, partials);
    hipLaunchKernelGGL(k_main, dim3(NCH, B), dim3(NTHR), 0, stream,
                       f0, mod_index, freq_ratio, adsr, partials, out);
  }
}